// Round 6
// baseline (51.960 us; speedup 1.0000x reference)
//
#include <hip/hip_runtime.h>

// out[b,d,s] = x[b,d,s] + sum_f phase_one_hot[b,f,s] * emb_weight[f,d]
// B=16, F=9, S=4096, D=512. Memory-bound streaming op.
//
// R6: test the last unfalsified hypothesis — p re-read fabric contention.
// DPER 8 -> 32 cuts p L2/fabric amplification 64x -> 16x (154 MB -> 38 MB).
// Depth-2 software pipeline (prefetch x[k+1] during compute/store of k),
// plain stores only (R4 proved nt stores are flakily non-coherent).
// Evidence so far: DPER8=48.1/49.4us, DPER16(nt)=45.3, forced-ILP no help.
// Floor = 270 MB / 6.29 TB/s = 43 us.

#define PE_B 16
#define PE_F 9
#define PE_S 4096
#define PE_D 512
#define PE_DPER 32
#define PE_BLOCK 256

typedef float f32x4 __attribute__((ext_vector_type(4)));

__global__ __launch_bounds__(PE_BLOCK) void PhaseEncoding_46918222742189_kernel(
    const float* __restrict__ x,
    const float* __restrict__ p,
    const float* __restrict__ w,
    float* __restrict__ out)
{
    // grid: x = S/4/PE_BLOCK (s-chunks), y = D/PE_DPER, z = B
    const int tid = threadIdx.x;
    const int s   = (blockIdx.x * PE_BLOCK + tid) * 4;  // first s of this thread's float4
    const int d0  = blockIdx.y * PE_DPER;
    const int b   = blockIdx.z;

    const float* pb = p   + ((size_t)b * PE_F) * PE_S + s;
    const float* xb = x   + ((size_t)b * PE_D + d0) * PE_S + s;
    float*       ob = out + ((size_t)b * PE_D + d0) * PE_S + s;

    // p[b, f, s..s+3] for all 9 f (coalesced; p is 2.4MB -> L2/L3 resident;
    // loaded once per thread, reused for 32 d values)
    f32x4 pv[PE_F];
#pragma unroll
    for (int f = 0; f < PE_F; ++f)
        pv[f] = *reinterpret_cast<const f32x4*>(pb + (size_t)f * PE_S);

    // depth-2 pipeline over d: prefetch x[k+1] while computing/storing k
    f32x4 cur = *reinterpret_cast<const f32x4*>(xb);
#pragma unroll
    for (int k = 0; k < PE_DPER; ++k) {
        f32x4 nxt;
        if (k + 1 < PE_DPER)
            nxt = *reinterpret_cast<const f32x4*>(xb + (size_t)(k + 1) * PE_S);
        const int d = d0 + k;
        float a0 = cur.x, a1 = cur.y, a2 = cur.z, a3 = cur.w;
#pragma unroll
        for (int f = 0; f < PE_F; ++f) {
            // wave-uniform index -> scalar load via constant cache, ~free
            const float wv = w[f * PE_D + d];
            a0 = fmaf(pv[f].x, wv, a0);
            a1 = fmaf(pv[f].y, wv, a1);
            a2 = fmaf(pv[f].z, wv, a2);
            a3 = fmaf(pv[f].w, wv, a3);
        }
        f32x4 ov = {a0, a1, a2, a3};
        *reinterpret_cast<f32x4*>(ob + (size_t)k * PE_S) = ov;
        cur = nxt;
    }
}

extern "C" void kernel_launch(void* const* d_in, const int* in_sizes, int n_in,
                              void* d_out, int out_size, void* d_ws, size_t ws_size,
                              hipStream_t stream) {
    const float* x = (const float*)d_in[0];   // (B, D, S) f32
    const float* p = (const float*)d_in[1];   // (B, F, S) f32
    const float* w = (const float*)d_in[2];   // (F, D)   f32
    float* out = (float*)d_out;               // (B, D, S) f32

    dim3 grid(PE_S / 4 / PE_BLOCK,   // 4 s-chunks
              PE_D / PE_DPER,        // 16 d-groups
              PE_B);                 // 16 batches
    PhaseEncoding_46918222742189_kernel<<<grid, dim3(PE_BLOCK), 0, stream>>>(x, p, w, out);
}

// Round 7
// 48.550 us; speedup vs baseline: 1.0702x; 1.0702x over previous
//
#include <hip/hip_runtime.h>

// out[b,d,s] = x[b,d,s] + sum_f phase_one_hot[b,f,s] * emb_weight[f,d]
// B=16, F=9, S=4096, D=512. Memory-bound streaming op.
//
// FINAL (= R1, best correct config at 48.09 us).
// Evidence trail across R1-R6:
//  - DPER in {8,16,32}, forced-ILP, depth-2 pipeline: all 48-52 us.
//    DPER=8 with compiler-chosen schedule is the best correct config.
//  - nt stores gained ~4 us (L3 pollution) but FAILED the post-timing
//    coherence re-check in R4 (stale lines after graph replay) - banned.
//  - Roofline: 270 MB irreducible (x 134 read + out 134 write + p) at the
//    ~6.3 TB/s measured mixed-stream ceiling = 43 us floor; 48 us = ~89%.

#define PE_B 16
#define PE_F 9
#define PE_S 4096
#define PE_D 512
#define PE_DPER 8
#define PE_BLOCK 256

__global__ __launch_bounds__(PE_BLOCK) void PhaseEncoding_46918222742189_kernel(
    const float* __restrict__ x,
    const float* __restrict__ p,
    const float* __restrict__ w,
    float* __restrict__ out)
{
    // grid: x = S/4/PE_BLOCK (s-chunks), y = D/PE_DPER, z = B
    const int tid = threadIdx.x;
    const int s   = (blockIdx.x * PE_BLOCK + tid) * 4;  // first s of this thread's float4
    const int d0  = blockIdx.y * PE_DPER;
    const int b   = blockIdx.z;

    // Load p[b, f, s..s+3] for all 9 f into registers (coalesced float4 loads;
    // p is 2.4 MB total -> L2/L3-resident for the 64x re-reads across d-groups).
    float4 pv[PE_F];
    const float* pb = p + ((size_t)b * PE_F) * PE_S + s;
#pragma unroll
    for (int f = 0; f < PE_F; ++f)
        pv[f] = *reinterpret_cast<const float4*>(pb + (size_t)f * PE_S);

    const float* xb = x   + ((size_t)b * PE_D + d0) * PE_S + s;
    float*       ob = out + ((size_t)b * PE_D + d0) * PE_S + s;

#pragma unroll
    for (int k = 0; k < PE_DPER; ++k) {
        const int d = d0 + k;
        float4 xv = *reinterpret_cast<const float4*>(xb + (size_t)k * PE_S);
        float a0 = 0.f, a1 = 0.f, a2 = 0.f, a3 = 0.f;
#pragma unroll
        for (int f = 0; f < PE_F; ++f) {
            // wave-uniform index (no threadIdx) -> scalar load, L1/K$ cached
            const float wv = w[f * PE_D + d];
            a0 = fmaf(pv[f].x, wv, a0);
            a1 = fmaf(pv[f].y, wv, a1);
            a2 = fmaf(pv[f].z, wv, a2);
            a3 = fmaf(pv[f].w, wv, a3);
        }
        float4 ov = make_float4(xv.x + a0, xv.y + a1, xv.z + a2, xv.w + a3);
        *reinterpret_cast<float4*>(ob + (size_t)k * PE_S) = ov;
    }
}

extern "C" void kernel_launch(void* const* d_in, const int* in_sizes, int n_in,
                              void* d_out, int out_size, void* d_ws, size_t ws_size,
                              hipStream_t stream) {
    const float* x = (const float*)d_in[0];   // (B, D, S) f32
    const float* p = (const float*)d_in[1];   // (B, F, S) f32
    const float* w = (const float*)d_in[2];   // (F, D)   f32
    float* out = (float*)d_out;               // (B, D, S) f32

    dim3 grid(PE_S / 4 / PE_BLOCK,   // 4 s-chunks
              PE_D / PE_DPER,        // 64 d-groups
              PE_B);                 // 16 batches
    PhaseEncoding_46918222742189_kernel<<<grid, dim3(PE_BLOCK), 0, stream>>>(x, p, w, out);
}